// Round 2
// baseline (377.502 us; speedup 1.0000x reference)
//
#include <hip/hip_runtime.h>
#include <hip/hip_bf16.h>
#include <stdint.h>

#define N_TOK 8192
#define D 128
#define NSPLIT 4
#define QTILES (N_TOK / 16)  // 512

typedef __attribute__((ext_vector_type(8))) short short8;   // bf16x8 MFMA frag
typedef __attribute__((ext_vector_type(4))) short short4v;  // 4 bf16 (8B store)
typedef __attribute__((ext_vector_type(4))) float f32x4;    // MFMA accum

__device__ __forceinline__ ushort f2bf(float f) {
    union { float f; uint32_t u; } cv; cv.f = f;
    uint32_t u = cv.u;
    return (ushort)((u + 0x7fffu + ((u >> 16) & 1u)) >> 16);  // RNE
}
__device__ __forceinline__ float bf2f(ushort h) {
    union { uint32_t u; float f; } cv; cv.u = ((uint32_t)h) << 16;
    return cv.f;
}
__device__ __forceinline__ f32x4 zero4() {
    f32x4 z; z[0] = 0.f; z[1] = 0.f; z[2] = 0.f; z[3] = 0.f; return z;
}

// -------- kernel 1: f32 -> double-bf16 split (X and the 3 weights) ----------
__global__ void cvt_kernel(const float* __restrict__ X, const float* __restrict__ Wq,
                           const float* __restrict__ Wk, const float* __restrict__ Wv,
                           ushort* __restrict__ Xhi, ushort* __restrict__ Xlo,
                           ushort* __restrict__ Whi, ushort* __restrict__ Wlo, int nX) {
    int i = blockIdx.x * blockDim.x + threadIdx.x;
    int e = i * 4;
    int total = nX + 3 * 16384;
    if (e >= total) return;
    const float* src; ushort* dhi; ushort* dlo; int off;
    if (e < nX) { src = X; dhi = Xhi; dlo = Xlo; off = e; }
    else {
        int w = e - nX;
        int m = w >> 14;
        off = w & 16383;
        src = (m == 0) ? Wq : ((m == 1) ? Wk : Wv);
        dhi = Whi + (m << 14);
        dlo = Wlo + (m << 14);
    }
    f32x4 v = *(const f32x4*)(src + off);
    short4v ph, pl;
    #pragma unroll
    for (int r = 0; r < 4; ++r) {
        ushort h = f2bf(v[r]);
        ph[r] = (short)h;
        pl[r] = (short)f2bf(v[r] - bf2f(h));
    }
    *(short4v*)(dhi + off) = ph;
    *(short4v*)(dlo + off) = pl;
}

// -------- kernel 2: projections via MFMA (double-bf16 inputs) ---------------
// Q^T = Wq * X^T, K^T = Wk * X^T  (swapped so store is row-major Q/K, 8B packs)
// Q,K stored as hi/lo bf16 pairs; V single bf16, stored transposed Vt[128][N].
__global__ __launch_bounds__(64) void proj_kernel(
    const ushort* __restrict__ Xhi, const ushort* __restrict__ Xlo,
    const ushort* __restrict__ Whi, const ushort* __restrict__ Wlo,
    ushort* __restrict__ Qhi, ushort* __restrict__ Qlo,
    ushort* __restrict__ Khi, ushort* __restrict__ Klo, ushort* __restrict__ Vt) {
    const int lane = threadIdx.x & 63;
    const int g = lane >> 4, r16 = lane & 15;
    const int nbase = blockIdx.x * 16;

    short8 xh[4], xl[4];
    const ushort* xrh = Xhi + (size_t)(nbase + r16) * D + 8 * g;
    const ushort* xrl = Xlo + (size_t)(nbase + r16) * D + 8 * g;
    #pragma unroll
    for (int ds = 0; ds < 4; ++ds) {
        xh[ds] = *(const short8*)(xrh + 32 * ds);
        xl[ds] = *(const short8*)(xrl + 32 * ds);
    }

    #pragma unroll
    for (int m = 0; m < 2; ++m) {
        const ushort* Wh = Whi + m * 16384;
        const ushort* Wl = Wlo + m * 16384;
        ushort* Oh = m ? Khi : Qhi;
        ushort* Ol = m ? Klo : Qlo;
        #pragma unroll
        for (int jt = 0; jt < 8; ++jt) {
            f32x4 acc = zero4();
            const ushort* wrh = Wh + (size_t)(16 * jt + r16) * D + 8 * g;
            const ushort* wrl = Wl + (size_t)(16 * jt + r16) * D + 8 * g;
            #pragma unroll
            for (int ds = 0; ds < 4; ++ds) {
                short8 wh = *(const short8*)(wrh + 32 * ds);
                short8 wl = *(const short8*)(wrl + 32 * ds);
                acc = __builtin_amdgcn_mfma_f32_16x16x32_bf16(wh, xh[ds], acc, 0, 0, 0);
                acc = __builtin_amdgcn_mfma_f32_16x16x32_bf16(wh, xl[ds], acc, 0, 0, 0);
                acc = __builtin_amdgcn_mfma_f32_16x16x32_bf16(wl, xh[ds], acc, 0, 0, 0);
            }
            short4v ph, pl;
            #pragma unroll
            for (int r = 0; r < 4; ++r) {
                ushort h = f2bf(acc[r]);
                ph[r] = (short)h;
                pl[r] = (short)f2bf(acc[r] - bf2f(h));
            }
            // lane holds rows j=16jt+4g+r, col n=nbase+r16
            size_t oo = (size_t)(nbase + r16) * D + 16 * jt + 4 * g;
            *(short4v*)(Oh + oo) = ph;
            *(short4v*)(Ol + oo) = pl;
        }
    }
    {
        const ushort* Wh = Whi + 32768;
        const ushort* Wl = Wlo + 32768;
        #pragma unroll
        for (int jt = 0; jt < 8; ++jt) {
            f32x4 acc = zero4();
            const ushort* wrh = Wh + (size_t)(16 * jt + r16) * D + 8 * g;
            const ushort* wrl = Wl + (size_t)(16 * jt + r16) * D + 8 * g;
            #pragma unroll
            for (int ds = 0; ds < 4; ++ds) {
                short8 wh = *(const short8*)(wrh + 32 * ds);
                short8 wl = *(const short8*)(wrl + 32 * ds);
                acc = __builtin_amdgcn_mfma_f32_16x16x32_bf16(xh[ds], wh, acc, 0, 0, 0);
                acc = __builtin_amdgcn_mfma_f32_16x16x32_bf16(xl[ds], wh, acc, 0, 0, 0);
                acc = __builtin_amdgcn_mfma_f32_16x16x32_bf16(xh[ds], wl, acc, 0, 0, 0);
            }
            short4v pk;
            #pragma unroll
            for (int r = 0; r < 4; ++r) pk[r] = (short)f2bf(acc[r]);
            // lane holds V[n=nbase+4g+r][j=16jt+r16] -> Vt[j][n], 4 consecutive n
            *(short4v*)(Vt + (size_t)(16 * jt + r16) * N_TOK + nbase + 4 * g) = pk;
        }
    }
}

// -------- kernel 3: flash attention (split-KV partials) ---------------------
// Per 64-thread block (1 wave): 16 q rows, iterate KV in 64-row tiles.
// S^T = K*Q^T in double-bf16 (3 MFMAs) -> q = lane&15 has lane-local softmax.
// O^T = V^T*P^T (q = lane&15 -> lane-local rescale; float4 epilogue)
__global__ __launch_bounds__(64) void flash_kernel(
    const ushort* __restrict__ Qhi, const ushort* __restrict__ Qlo,
    const ushort* __restrict__ Khi, const ushort* __restrict__ Klo,
    const ushort* __restrict__ Vt, float* __restrict__ Op, float* __restrict__ ML) {
    __shared__ __align__(16) ushort P_lds[16 * 64];
    const int lane = threadIdx.x & 63;
    const int g = lane >> 4, r16 = lane & 15;
    const int qt = blockIdx.x & (QTILES - 1);
    const int sp = blockIdx.x >> 9;            // QTILES == 512
    const int qbase = qt * 16;
    const int kv0 = sp * (N_TOK / NSPLIT);
    const int kv1 = kv0 + (N_TOK / NSPLIT);
    const int swz = (r16 & 7) << 3;            // XOR swizzle, bank-conflict fix

    short8 qh[4], ql[4];
    const ushort* qrh = Qhi + (size_t)(qbase + r16) * D + 8 * g;
    const ushort* qrl = Qlo + (size_t)(qbase + r16) * D + 8 * g;
    #pragma unroll
    for (int ds = 0; ds < 4; ++ds) {
        qh[ds] = *(const short8*)(qrh + 32 * ds);
        ql[ds] = *(const short8*)(qrl + 32 * ds);
    }

    float m = -INFINITY, l = 0.f;
    f32x4 o[8];
    #pragma unroll
    for (int dt = 0; dt < 8; ++dt) o[dt] = zero4();

    for (int kv = kv0; kv < kv1; kv += 64) {
        // --- S^T = K*Q^T : 4 k-tiles x 4 d-slices x 3 split terms
        f32x4 s[4];
        #pragma unroll
        for (int t = 0; t < 4; ++t) {
            s[t] = zero4();
            const ushort* krh = Khi + (size_t)(kv + 16 * t + r16) * D + 8 * g;
            const ushort* krl = Klo + (size_t)(kv + 16 * t + r16) * D + 8 * g;
            #pragma unroll
            for (int ds = 0; ds < 4; ++ds) {
                short8 kh = *(const short8*)(krh + 32 * ds);
                short8 kl = *(const short8*)(krl + 32 * ds);
                s[t] = __builtin_amdgcn_mfma_f32_16x16x32_bf16(kh, qh[ds], s[t], 0, 0, 0);
                s[t] = __builtin_amdgcn_mfma_f32_16x16x32_bf16(kh, ql[ds], s[t], 0, 0, 0);
                s[t] = __builtin_amdgcn_mfma_f32_16x16x32_bf16(kl, qh[ds], s[t], 0, 0, 0);
            }
        }
        // --- online softmax: lane holds 16 scores of its own q-row
        float tm = -INFINITY;
        #pragma unroll
        for (int t = 0; t < 4; ++t) {
            #pragma unroll
            for (int r = 0; r < 4; ++r) tm = fmaxf(tm, s[t][r]);
        }
        tm = fmaxf(tm, __shfl_xor(tm, 16));
        tm = fmaxf(tm, __shfl_xor(tm, 32));
        float mnew = fmaxf(m, tm);
        float scale = __expf(m - mnew);
        float psum = 0.f;
        ushort pb[16];
        #pragma unroll
        for (int t = 0; t < 4; ++t) {
            #pragma unroll
            for (int r = 0; r < 4; ++r) {
                float p = __expf(s[t][r] - mnew);
                psum += p;
                pb[4 * t + r] = f2bf(p);
            }
        }
        psum += __shfl_xor(psum, 16);
        psum += __shfl_xor(psum, 32);
        l = l * scale + psum;
        m = mnew;
        #pragma unroll
        for (int dt = 0; dt < 8; ++dt) o[dt] *= scale;
        // --- P -> LDS (lane writes 4 consecutive kpos of its q-row, swizzled)
        #pragma unroll
        for (int t = 0; t < 4; ++t) {
            short4v pk;
            #pragma unroll
            for (int r = 0; r < 4; ++r) pk[r] = (short)pb[4 * t + r];
            *(short4v*)&P_lds[(r16 * 64 + 16 * t + 4 * g) ^ swz] = pk;
        }
        // --- O^T += V^T * P^T : 2 kpos chunks x 8 d-tiles
        #pragma unroll
        for (int c = 0; c < 2; ++c) {
            short8 pf = *(const short8*)&P_lds[(r16 * 64 + 32 * c + 8 * g) ^ swz];
            const ushort* vcol = Vt + (size_t)r16 * N_TOK + kv + 32 * c + 8 * g;
            #pragma unroll
            for (int dt = 0; dt < 8; ++dt) {
                short8 vf = *(const short8*)(vcol + (size_t)(16 * dt) * N_TOK);
                o[dt] = __builtin_amdgcn_mfma_f32_16x16x32_bf16(vf, pf, o[dt], 0, 0, 0);
            }
        }
    }
    // --- epilogue: partial O (pre-division) + (m, l)
    float* obase = Op + ((size_t)sp * N_TOK + qbase + r16) * D + 4 * g;
    #pragma unroll
    for (int dt = 0; dt < 8; ++dt) *(f32x4*)(obase + 16 * dt) = o[dt];
    if (g == 0) {
        float* ml = ML + ((size_t)sp * QTILES + qt) * 32;
        ml[r16] = m;
        ml[16 + r16] = l;
    }
}

// -------- kernel 4: merge the NSPLIT KV-split partials -----------------------
__global__ void merge_kernel(const float* __restrict__ Op, const float* __restrict__ ML,
                             float* __restrict__ out) {
    int i = blockIdx.x * blockDim.x + threadIdx.x;
    int e = i * 4;
    if (e >= N_TOK * D) return;
    int q = e >> 7;
    int qt = q >> 4, qr = q & 15;
    float mv[NSPLIT], lv[NSPLIT];
    float M = -INFINITY;
    #pragma unroll
    for (int s = 0; s < NSPLIT; ++s) {
        const float* ml = ML + ((size_t)s * QTILES + qt) * 32;
        mv[s] = ml[qr];
        lv[s] = ml[16 + qr];
        M = fmaxf(M, mv[s]);
    }
    float L = 0.f, a[NSPLIT];
    #pragma unroll
    for (int s = 0; s < NSPLIT; ++s) { a[s] = __expf(mv[s] - M); L += a[s] * lv[s]; }
    float inv = 1.f / L;
    f32x4 acc = zero4();
    #pragma unroll
    for (int s = 0; s < NSPLIT; ++s) {
        f32x4 ov = *(const f32x4*)(Op + (size_t)s * N_TOK * D + e);
        acc += ov * a[s];
    }
    *(f32x4*)(out + e) = acc * inv;
}

extern "C" void kernel_launch(void* const* d_in, const int* in_sizes, int n_in,
                              void* d_out, int out_size, void* d_ws, size_t ws_size,
                              hipStream_t stream) {
    const float* X  = (const float*)d_in[0];
    const float* Wq = (const float*)d_in[1];
    const float* Wk = (const float*)d_in[2];
    const float* Wv = (const float*)d_in[3];
    float* out = (float*)d_out;

    char* ws = (char*)d_ws;
    ushort* Xhi = (ushort*)(ws);                   // 2 MB
    ushort* Xlo = (ushort*)(ws + 2097152);         // 2 MB
    ushort* Whi = (ushort*)(ws + 4194304);         // 96 KB
    ushort* Wlo = (ushort*)(ws + 4292608);         // 96 KB
    ushort* Qhi = (ushort*)(ws + 4390912);         // 2 MB
    ushort* Qlo = (ushort*)(ws + 6488064);         // 2 MB
    ushort* Khi = (ushort*)(ws + 8585216);         // 2 MB
    ushort* Klo = (ushort*)(ws + 10682368);        // 2 MB
    ushort* Vt  = (ushort*)(ws + 12779520);        // 2 MB (transposed V)
    float*  Op  = (float*) (ws + 14876672);        // 16 MB (NSPLIT partials)
    float*  ML  = (float*) (ws + 31653888);        // 256 KB (m,l per split/qtile)

    int nX = N_TOK * D;
    int total4 = (nX + 3 * 16384) / 4;
    cvt_kernel<<<(total4 + 255) / 256, 256, 0, stream>>>(X, Wq, Wk, Wv, Xhi, Xlo, Whi, Wlo, nX);
    proj_kernel<<<QTILES, 64, 0, stream>>>(Xhi, Xlo, Whi, Wlo, Qhi, Qlo, Khi, Klo, Vt);
    flash_kernel<<<QTILES * NSPLIT, 64, 0, stream>>>(Qhi, Qlo, Khi, Klo, Vt, Op, ML);
    merge_kernel<<<(N_TOK * D / 4 + 255) / 256, 256, 0, stream>>>(Op, ML, out);
}